// Round 1
// baseline (9854.756 us; speedup 1.0000x reference)
//
#include <hip/hip_runtime.h>
#include <hip/hip_bf16.h>

// CrystalGraphConvNet forward, MI355X. All tensors FLOAT32.
// d_out = [out(2000), x(6.4M)] float32.
//
// Decomposition: gated = S[i] + T[nbr_idx[i,j]] + e_ij @ W_edge, with
// S = x@W[0:64]+b, T = x@W[64:128] precomputed per atom per layer.
// BN over batch => stats pass + apply pass (recompute, no 614MB gated buffer).
//
// R5 change: two-pass channel-half split in both edge kernels.
// R4 evidence: VGPR_Count=60 < 82 named weights, occupancy 38.5% (=3 waves/SIMD
// = 512/~156 total regs), VALU issue 2.7x over static count => compiler spilled
// the 82 weights to AGPRs (hidden from VGPR_Count, v_accvgpr_read per use).
// Fix: (a) each wave runs pass A (lo channels, 41 weights, sigmoid/filter) then
// pass B (hi channels, other 41 weights, tanh/core); weight loads live inside
// each pass and are pinned with empty volatile asm so live set stays ~65 VGPRs.
// (b) edge-feature rows are wave-uniform -> scalar s_loads into SGPRs, killing
// the 41 v_readlane broadcasts per edge. (c) apply stashes the 12 per-edge
// filter values in LDS (same-wave, conflict-free) between passes.

#define NA    100000
#define MN    12
#define NC    2000
#define ORIGF 92
#define NBRF  41
#define FD    64
#define NBLK  3125     // edge-kernel blocks: 3125 * 32 atoms = 100000 exactly
#define EPSF  1e-5f

#define REP28(X) X(0)X(1)X(2)X(3)X(4)X(5)X(6)X(7)X(8)X(9)X(10)X(11)X(12)X(13)X(14)X(15)X(16)X(17)X(18)X(19)X(20)X(21)X(22)X(23)X(24)X(25)X(26)X(27)
#define REP41(X) X(0)X(1)X(2)X(3)X(4)X(5)X(6)X(7)X(8)X(9)X(10)X(11)X(12)X(13)X(14)X(15)X(16)X(17)X(18)X(19)X(20)X(21)X(22)X(23)X(24)X(25)X(26)X(27)X(28)X(29)X(30)X(31)X(32)X(33)X(34)X(35)X(36)X(37)X(38)X(39)X(40)
#define REP64(X) X(0)X(1)X(2)X(3)X(4)X(5)X(6)X(7)X(8)X(9)X(10)X(11)X(12)X(13)X(14)X(15)X(16)X(17)X(18)X(19)X(20)X(21)X(22)X(23)X(24)X(25)X(26)X(27)X(28)X(29)X(30)X(31)X(32)X(33)X(34)X(35)X(36)X(37)X(38)X(39)X(40)X(41)X(42)X(43)X(44)X(45)X(46)X(47)X(48)X(49)X(50)X(51)X(52)X(53)X(54)X(55)X(56)X(57)X(58)X(59)X(60)X(61)X(62)X(63)

typedef const float* fp;

__device__ __forceinline__ float rlf(float v, int q){
  return __int_as_float(__builtin_amdgcn_readlane(__float_as_int(v), q));
}
__device__ __forceinline__ float fsig(float z){
  z = fminf(fmaxf(z, -30.f), 30.f);
  return 1.f / (1.f + __expf(-z));
}
__device__ __forceinline__ float ftanh(float z){
  z = fminf(fmaxf(z, -15.f), 15.f);
  float e = __expf(2.f * z);
  return (e - 1.f) / (e + 1.f);
}

// ---------------- zero scratch ----------------
__global__ void zero_kernel(float* __restrict__ p, int n){
  for (int i = blockIdx.x * blockDim.x + threadIdx.x; i < n; i += gridDim.x * blockDim.x)
    p[i] = 0.f;
}

// ---------------- embedding: x = atom_fea @ emb_W + emb_b ----------------
// wave per 8 atoms; lane = output channel (64). 92 W regs named -> VGPRs.
__global__ __launch_bounds__(256, 4) void emb_kernel(
    fp __restrict__ af, fp __restrict__ W, fp __restrict__ b,
    float* __restrict__ x)
{
  const int lane = threadIdx.x & 63, w = threadIdx.x >> 6;
#define EA(k) float wa##k = W[k * FD + lane];
  REP64(EA)
#undef EA
#define EB(k) float wb##k = W[(k + 64) * FD + lane];
  REP28(EB)
#undef EB
  const float bias = b[lane];
  const int base = blockIdx.x * 32 + w * 8;
  #pragma unroll 1
  for (int it = 0; it < 8; ++it){
    const int i = base + it;
    float ev0 = af[i * ORIGF + lane];
    float ev1 = (lane < 28) ? af[i * ORIGF + 64 + lane] : 0.f;
    float acc = bias;
#define FA(k) acc = fmaf(rlf(ev0, k), wa##k, acc);
    REP64(FA)
#undef FA
#define FB(k) acc = fmaf(rlf(ev1, k), wb##k, acc);
    REP28(FB)
#undef FB
    x[i * FD + lane] = acc;
  }
}

// ---------------- stw: out[N][128] = xin[N][64] @ W[64][128] (+bias) ----------------
// 1 output channel per lane (64 W regs). Wave pair covers both halves;
// block = 4 waves = 2 pairs x 16 atoms = 32 atoms.
__global__ __launch_bounds__(256, 4) void stw_kernel(
    const float* __restrict__ xin, fp __restrict__ W, fp __restrict__ bias,
    float* __restrict__ out)
{
  const int lane = threadIdx.x & 63, w = threadIdx.x >> 6;
  const int ch = (w & 1) * 64 + lane;
#define SW(k) float wv##k = W[k * 128 + ch];
  REP64(SW)
#undef SW
  const float bb = bias ? bias[ch] : 0.f;
  const int base = blockIdx.x * 32 + (w >> 1) * 16;
  #pragma unroll 1
  for (int it = 0; it < 16; ++it){
    const int i = base + it;
    float xv = xin[i * FD + lane];
    float acc = bb;
#define SF(k) acc = fmaf(rlf(xv, k), wv##k, acc);
    REP64(SF)
#undef SF
    out[i * 128 + ch] = acc;
  }
}

// ---------------- edge stats: accumulate sum/sumsq of gated over all N*M rows ----------------
// Two passes per atom: pass A = channels 0..63 (41 weights live), pass B =
// channels 64..127. Edge features read as wave-uniform scalar loads (SGPRs).
__global__ __launch_bounds__(256, 4) void edge_stats_kernel(
    const float* __restrict__ S, const float* __restrict__ T,
    fp __restrict__ nbr, const int* __restrict__ idx,
    fp __restrict__ We, float* __restrict__ p1)   // p1: [NBLK][256] coalesced
{
  const int lane = threadIdx.x & 63;
  const int w = __builtin_amdgcn_readfirstlane(threadIdx.x >> 6);
  float sum_lo = 0.f, ssq_lo = 0.f, sum_hi = 0.f, ssq_hi = 0.f;
  const int base = blockIdx.x * 32 + w * 8;
  #pragma unroll 1
  for (int it = 0; it < 8; ++it){
    const int i = base + it;
    fp nb = nbr + (size_t)i * (MN * NBRF);          // wave-uniform
    int kk = (lane < MN) ? idx[i * MN + lane] : 0;
    // ---- pass A: channels 0..63
    {
      const float s0 = S[i * 128 + lane];
#define LWA(q) float wl##q = We[q * 128 + lane]; asm volatile("" : "+v"(wl##q));
      REP41(LWA)
#undef LWA
      int k0 = __builtin_amdgcn_readlane(kk, 0);
      float t = T[k0 * 128 + lane];
      #pragma unroll 1
      for (int j = 0; j < MN; ++j){
        float t_n = 0.f;
        if (j + 1 < MN){
          int kn = __builtin_amdgcn_readlane(kk, j + 1);
          t_n = T[kn * 128 + lane];
        }
        fp e = nb + j * NBRF;                       // scalar loads
        float g = s0 + t;
#define FMA(q) g = fmaf(e[q], wl##q, g);
        REP41(FMA)
#undef FMA
        sum_lo += g; ssq_lo = fmaf(g, g, ssq_lo);
        t = t_n;
      }
    }
    // ---- pass B: channels 64..127
    {
      const float s1 = S[i * 128 + 64 + lane];
#define LWB(q) float wh##q = We[q * 128 + 64 + lane]; asm volatile("" : "+v"(wh##q));
      REP41(LWB)
#undef LWB
      int k0 = __builtin_amdgcn_readlane(kk, 0);
      float t = T[k0 * 128 + 64 + lane];
      #pragma unroll 1
      for (int j = 0; j < MN; ++j){
        float t_n = 0.f;
        if (j + 1 < MN){
          int kn = __builtin_amdgcn_readlane(kk, j + 1);
          t_n = T[kn * 128 + 64 + lane];
        }
        fp e = nb + j * NBRF;
        float g = s1 + t;
#define FMB(q) g = fmaf(e[q], wh##q, g);
        REP41(FMB)
#undef FMB
        sum_hi += g; ssq_hi = fmaf(g, g, ssq_hi);
        t = t_n;
      }
    }
  }
  __shared__ float red[4 * 512];
  red[w * 512 + 2 * lane           ] = sum_lo;
  red[w * 512 + 2 * lane + 1       ] = ssq_lo;
  red[w * 512 + 2 * (lane + 64)    ] = sum_hi;
  red[w * 512 + 2 * (lane + 64) + 1] = ssq_hi;
  __syncthreads();
  const int t = threadIdx.x;            // stat id: (t>>7)*128 channels = sum|ssq
  const int ch = t & 127, which = t >> 7;
  float v = 0.f;
  #pragma unroll
  for (int ww = 0; ww < 4; ++ww) v += red[ww * 512 + 2 * ch + which];
  p1[blockIdx.x * 256 + t] = v;
}

// ---------------- edge apply: gated -> BN1 affine -> sig*tanh -> sum_j ----------------
// Same two-pass split; pass A stashes the 12 per-edge filter values in LDS
// (same wave writes & reads -> no barrier), pass B combines with cores.
__global__ __launch_bounds__(256, 4) void edge_apply_kernel(
    const float* __restrict__ S, const float* __restrict__ T,
    fp __restrict__ nbr, const int* __restrict__ idx,
    fp __restrict__ We, const float* __restrict__ ss1,
    float* __restrict__ ns, float* __restrict__ p2)   // p2: [NBLK][128]
{
  const int lane = threadIdx.x & 63;
  const int w = __builtin_amdgcn_readfirstlane(threadIdx.x >> 6);
  __shared__ float fst[4][MN][64];                     // filter stash, conflict-free
  const float sc_lo = ss1[lane],      sh_lo = ss1[128 + lane];
  const float sc_hi = ss1[64 + lane], sh_hi = ss1[192 + lane];
  float sum2 = 0.f, ssq2 = 0.f;
  const int base = blockIdx.x * 32 + w * 8;
  #pragma unroll 1
  for (int it = 0; it < 8; ++it){
    const int i = base + it;
    fp nb = nbr + (size_t)i * (MN * NBRF);             // wave-uniform
    int kk = (lane < MN) ? idx[i * MN + lane] : 0;
    // ---- pass A: channels 0..63 -> filters
    {
      const float s0 = S[i * 128 + lane];
#define LWA(q) float wl##q = We[q * 128 + lane]; asm volatile("" : "+v"(wl##q));
      REP41(LWA)
#undef LWA
      int k0 = __builtin_amdgcn_readlane(kk, 0);
      float t = T[k0 * 128 + lane];
      #pragma unroll 1
      for (int j = 0; j < MN; ++j){
        float t_n = 0.f;
        if (j + 1 < MN){
          int kn = __builtin_amdgcn_readlane(kk, j + 1);
          t_n = T[kn * 128 + lane];
        }
        fp e = nb + j * NBRF;
        float g = s0 + t;
#define FMA(q) g = fmaf(e[q], wl##q, g);
        REP41(FMA)
#undef FMA
        fst[w][j][lane] = fsig(fmaf(g, sc_lo, sh_lo));
        t = t_n;
      }
    }
    // ---- pass B: channels 64..127 -> cores, combine
    float acc = 0.f;
    {
      const float s1 = S[i * 128 + 64 + lane];
#define LWB(q) float wh##q = We[q * 128 + 64 + lane]; asm volatile("" : "+v"(wh##q));
      REP41(LWB)
#undef LWB
      int k0 = __builtin_amdgcn_readlane(kk, 0);
      float t = T[k0 * 128 + 64 + lane];
      #pragma unroll 1
      for (int j = 0; j < MN; ++j){
        float t_n = 0.f;
        if (j + 1 < MN){
          int kn = __builtin_amdgcn_readlane(kk, j + 1);
          t_n = T[kn * 128 + 64 + lane];
        }
        fp e = nb + j * NBRF;
        float g = s1 + t;
#define FMB(q) g = fmaf(e[q], wh##q, g);
        REP41(FMB)
#undef FMB
        float core = ftanh(fmaf(g, sc_hi, sh_hi));
        acc = fmaf(fst[w][j][lane], core, acc);
        t = t_n;
      }
    }
    ns[i * FD + lane] = acc;
    sum2 += acc; ssq2 = fmaf(acc, acc, ssq2);
  }
  __shared__ float red[4 * 128];
  red[w * 128 + 2 * lane    ] = sum2;
  red[w * 128 + 2 * lane + 1] = ssq2;
  __syncthreads();
  const int t = threadIdx.x;
  if (t < 128){
    const int ch = t & 63, which = t >> 6;
    float v = 0.f;
    #pragma unroll
    for (int ww = 0; ww < 4; ++ww) v += red[ww * 128 + 2 * ch + which];
    p2[blockIdx.x * 128 + t] = v;
  }
}

// ---------------- grid reduce of partials (coalesced rows -> atomics, 64-way) ----------------
__global__ void reduce_rows_kernel(const float* __restrict__ p, float* __restrict__ accum,
                                   int nrows, int ncols)
{
  const int t = threadIdx.x;   // blockDim.x == ncols
  float a = 0.f;
  for (int r = blockIdx.x; r < nrows; r += gridDim.x) a += p[r * ncols + t];
  atomicAdd(&accum[t], a);
}

__global__ void finalize1_kernel(const float* __restrict__ acc, fp g, fp b,
                                 float* __restrict__ ss1)
{
  const int c = threadIdx.x;   // 128
  const float inv = 1.f / 1200000.f;
  float mean = acc[c] * inv;
  float var  = fmaxf(acc[128 + c] * inv - mean * mean, 0.f);
  float sc   = g[c] * rsqrtf(var + EPSF);
  ss1[c] = sc;
  ss1[128 + c] = b[c] - mean * sc;
}

__global__ void finalize2_kernel(const float* __restrict__ acc, fp g, fp b,
                                 float* __restrict__ ss2)
{
  const int c = threadIdx.x;   // 64
  const float inv = 1.f / 100000.f;
  float mean = acc[c] * inv;
  float var  = fmaxf(acc[64 + c] * inv - mean * mean, 0.f);
  float sc   = g[c] * rsqrtf(var + EPSF);
  ss2[c] = sc;
  ss2[64 + c] = b[c] - mean * sc;
}

// ---------------- BN2 affine + residual tanh; optional f32 x output copy ----------------
__global__ __launch_bounds__(256) void bn2res_kernel(
    float* __restrict__ x, const float* __restrict__ ns,
    const float* __restrict__ ss2, float* __restrict__ xout)
{
  const int e = (blockIdx.x * 256 + threadIdx.x) * 4;   // grid sized exactly
  const int c = e & 63;
  float4 xv = *(const float4*)(x + e);
  float4 nv = *(const float4*)(ns + e);
  float r0 = ftanh(fmaf(nv.x, ss2[c + 0], ss2[64 + c + 0]) + xv.x);
  float r1 = ftanh(fmaf(nv.y, ss2[c + 1], ss2[64 + c + 1]) + xv.y);
  float r2 = ftanh(fmaf(nv.z, ss2[c + 2], ss2[64 + c + 2]) + xv.z);
  float r3 = ftanh(fmaf(nv.w, ss2[c + 3], ss2[64 + c + 3]) + xv.w);
  *(float4*)(x + e) = make_float4(r0, r1, r2, r3);
  if (xout){
    *(float4*)(xout + e) = make_float4(r0, r1, r2, r3);
  }
}

// ---------------- pooling: per-crystal sum of x + counts (sorted ids, run-accumulate) ----------------
__global__ __launch_bounds__(256) void pool1_kernel(
    const float* __restrict__ x, const int* __restrict__ cid,
    float* __restrict__ csum, float* __restrict__ ccnt)
{
  const int lane = threadIdx.x & 63, w = threadIdx.x >> 6;
  const int wg = blockIdx.x * 4 + w;
  const int i0 = wg * 64;
  if (i0 >= NA) return;
  const int i1 = min(i0 + 64, NA);
  int cur = -1; float acc = 0.f; int run = 0;
  for (int i = i0; i < i1; ++i){
    int cd = cid[i];
    if (cd != cur){
      if (cur >= 0){
        atomicAdd(&csum[cur * FD + lane], acc);
        if (lane == 0) atomicAdd(&ccnt[cur], (float)run);
      }
      cur = cd; acc = 0.f; run = 0;
    }
    acc += x[i * FD + lane];
    run++;
  }
  if (cur >= 0){
    atomicAdd(&csum[cur * FD + lane], acc);
    if (lane == 0) atomicAdd(&ccnt[cur], (float)run);
  }
}

// ---------------- c3 = tanh(crys_mean @ W3 + b3) per crystal ----------------
__global__ void cm3_kernel(const float* __restrict__ csum, const float* __restrict__ ccnt,
                           fp W3, fp b3, float* __restrict__ c3)
{
  const int b = blockIdx.x, t = threadIdx.x;   // 64 threads
  __shared__ float mean[64];
  float inv = 1.f / fmaxf(ccnt[b], 1.f);
  mean[t] = csum[b * FD + t] * inv;
  __syncthreads();
  float acc = b3[t];
  #pragma unroll
  for (int k = 0; k < 64; k++) acc = fmaf(mean[k], W3[k * FD + t], acc);
  c3[b * FD + t] = ftanh(acc);
}

// ---------------- a = sigmoid(<x_i, c3[cid]>); seg-sum of a*x ----------------
__global__ __launch_bounds__(256) void pool2_kernel(
    const float* __restrict__ x, const int* __restrict__ cid,
    const float* __restrict__ c3, float* __restrict__ cfs)
{
  const int lane = threadIdx.x & 63, w = threadIdx.x >> 6;
  const int wg = blockIdx.x * 4 + w;
  const int i0 = wg * 64;
  if (i0 >= NA) return;
  const int i1 = min(i0 + 64, NA);
  int cur = -1; float acc = 0.f;
  for (int i = i0; i < i1; ++i){
    int cd = cid[i];
    if (cd != cur){
      if (cur >= 0) atomicAdd(&cfs[cur * FD + lane], acc);
      cur = cd; acc = 0.f;
    }
    float xv = x[i * FD + lane];
    float p = xv * c3[cd * FD + lane];
    #pragma unroll
    for (int off = 32; off; off >>= 1) p += __shfl_xor(p, off);
    acc = fmaf(fsig(p), xv, acc);
  }
  if (cur >= 0) atomicAdd(&cfs[cur * FD + lane], acc);
}

// ---------------- head: softplus(mean @ fc + b) @ out_W + out_b ----------------
__global__ void head_kernel(const float* __restrict__ cfs, const float* __restrict__ ccnt,
                            fp fcW, fp fcb, fp oW, fp ob,
                            float* __restrict__ outp)
{
  const int b = blockIdx.x, t = threadIdx.x;   // 128 threads
  __shared__ float row[64];
  __shared__ float red[128];
  float inv = 1.f / fmaxf(ccnt[b], 1.f);
  if (t < 64) row[t] = cfs[b * FD + t] * inv;
  __syncthreads();
  float acc = fcb[t];
  #pragma unroll
  for (int k = 0; k < 64; k++) acc = fmaf(row[k], fcW[k * 128 + t], acc);
  float sp = (acc > 20.f) ? acc : log1pf(__expf(acc));
  red[t] = sp * oW[t];
  __syncthreads();
  for (int off = 64; off; off >>= 1){
    if (t < off) red[t] += red[t + off];
    __syncthreads();
  }
  if (t == 0) outp[b] = red[0] + ob[0];
}

// ---------------- workspace layout (floats) ----------------
static const size_t O_X    = 0;            // 6,400,000   x[N][64]
static const size_t O_S    = 6400000;      // 12,800,000  S[N][128]
static const size_t O_T    = 19200000;     // 12,800,000  T[N][128]
static const size_t O_NS   = 32000000;     // 6,400,000   nbr_sumed[N][64]
static const size_t O_P1   = 38400000;     // 800,000     [NBLK][256]
static const size_t O_P2   = 39200000;     // 400,000     [NBLK][128]
static const size_t O_SS1  = 39600000;     // 256
static const size_t O_SS2  = 39600256;     // 128
static const size_t O_G1   = 39600384;     // 256
static const size_t O_G2   = 39600640;     // 128
static const size_t O_CSUM = 39600768;     // 128,000
static const size_t O_CCNT = 39728768;     // 2,000
static const size_t O_C3   = 39730768;     // 128,000
static const size_t O_CFS  = 39858768;     // 128,000
static const size_t O_END  = 39986768;     // ~160 MB

extern "C" void kernel_launch(void* const* d_in, const int* in_sizes, int n_in,
                              void* d_out, int out_size, void* d_ws, size_t ws_size,
                              hipStream_t stream)
{
  (void)in_sizes; (void)n_in; (void)out_size;
  if (ws_size < O_END * sizeof(float)) return;   // visible failure, no corruption

  fp atom_fea = (fp)d_in[0];
  fp nbr_fea  = (fp)d_in[1];
  const int* nbr_idx = (const int*)d_in[2];
  const int* cids    = (const int*)d_in[3];
  fp embW = (fp)d_in[4];
  fp embb = (fp)d_in[5];
  fp convW = (fp)d_in[6];
  fp convb = (fp)d_in[7];
  fp bn1g = (fp)d_in[8];
  fp bn1b = (fp)d_in[9];
  fp bn2g = (fp)d_in[10];
  fp bn2b = (fp)d_in[11];
  fp W3W  = (fp)d_in[12];
  fp W3b  = (fp)d_in[13];
  fp fcW  = (fp)d_in[14];
  fp fcb  = (fp)d_in[15];
  fp oW   = (fp)d_in[16];
  fp ob   = (fp)d_in[17];

  float* out_head = (float*)d_out;
  float* out_x    = out_head + NC;

  float* W  = (float*)d_ws;
  float* x    = W + O_X;
  float* S    = W + O_S;
  float* T    = W + O_T;
  float* ns   = W + O_NS;
  float* p1   = W + O_P1;
  float* p2   = W + O_P2;
  float* ss1  = W + O_SS1;
  float* ss2  = W + O_SS2;
  float* g1s  = W + O_G1;
  float* g2s  = W + O_G2;
  float* csum = W + O_CSUM;
  float* ccnt = W + O_CCNT;
  float* c3   = W + O_C3;
  float* cfs  = W + O_CFS;

  // zero crystal accumulators (csum..cfs contiguous, 386,000 floats)
  zero_kernel<<<128, 256, 0, stream>>>(csum, 386000);

  emb_kernel<<<NBLK, 256, 0, stream>>>(atom_fea, embW, embb, x);

  for (int l = 0; l < 3; ++l){
    fp Wl = convW + (size_t)l * 169 * 128;
    stw_kernel<<<NBLK, 256, 0, stream>>>(x, Wl,            convb + l * 128, S);  // self rows 0..63
    stw_kernel<<<NBLK, 256, 0, stream>>>(x, Wl + 64 * 128, (fp)nullptr,     T);  // nbr rows 64..127
    zero_kernel<<<1, 256, 0, stream>>>(g1s, 384);  // g1s(256)+g2s(128) contiguous
    edge_stats_kernel<<<NBLK, 256, 0, stream>>>(S, T, nbr_fea, nbr_idx, Wl + 128 * 128, p1);
    reduce_rows_kernel<<<64, 256, 0, stream>>>(p1, g1s, NBLK, 256);
    finalize1_kernel<<<1, 128, 0, stream>>>(g1s, bn1g + l * 128, bn1b + l * 128, ss1);
    edge_apply_kernel<<<NBLK, 256, 0, stream>>>(S, T, nbr_fea, nbr_idx, Wl + 128 * 128, ss1, ns, p2);
    reduce_rows_kernel<<<64, 128, 0, stream>>>(p2, g2s, NBLK, 128);
    finalize2_kernel<<<1, 64, 0, stream>>>(g2s, bn2g + l * 64, bn2b + l * 64, ss2);
    bn2res_kernel<<<6250, 256, 0, stream>>>(x, ns, ss2, (l == 2) ? out_x : (float*)nullptr);
  }

  pool1_kernel<<<391, 256, 0, stream>>>(x, cids, csum, ccnt);
  cm3_kernel<<<NC, 64, 0, stream>>>(csum, ccnt, W3W, W3b, c3);
  pool2_kernel<<<391, 256, 0, stream>>>(x, cids, c3, cfs);
  head_kernel<<<NC, 128, 0, stream>>>(cfs, ccnt, fcW, fcb, oW, ob, out_head);
}

// Round 2
// 3201.979 us; speedup vs baseline: 3.0777x; 3.0777x over previous
//
#include <hip/hip_runtime.h>
#include <hip/hip_bf16.h>

// CrystalGraphConvNet forward, MI355X. All tensors FLOAT32.
// d_out = [out(2000), x(6.4M)] float32.
//
// Decomposition: gated = S[i] + T[nbr_idx[i,j]] + e_ij @ W_edge, with
// S = x@W[0:64]+b, T = x@W[64:128] precomputed per atom per layer.
// BN over batch => stats pass + apply pass (recompute, no 614MB gated buffer).
//
// R6 change: REVERT R5's two-pass restructure (catastrophic: per-edge scalar-load
// drains serialized edge_stats to 20.9ms). Back to R4 structure verbatim, with ONE
// knob: __launch_bounds__(256, 2) on emb/edge kernels (was (256,4)).
// R4 evidence: VGPR_Count=60 < 82 named weights, occupancy 38.5% (3 waves/SIMD =
// 512/~156 total regs), VALU 2.7x inflated at 80% busy => allocator kept 60 arch
// VGPRs under the 128-reg (waves_per_eu=4) budget and spilled the 82 long-lived
// weights to AGPRs (unified file: hidden from VGPR_Count, v_accvgpr_read per use,
// occupancy still paid). waves_per_eu=2 => 256-reg budget => weights stay in true
// VGPRs (~115 total => 4 waves/SIMD), accvgpr-read tax gone.

#define NA    100000
#define MN    12
#define NC    2000
#define ORIGF 92
#define NBRF  41
#define FD    64
#define NBLK  3125     // edge-kernel blocks: 3125 * 32 atoms = 100000 exactly
#define EPSF  1e-5f

#define REP28(X) X(0)X(1)X(2)X(3)X(4)X(5)X(6)X(7)X(8)X(9)X(10)X(11)X(12)X(13)X(14)X(15)X(16)X(17)X(18)X(19)X(20)X(21)X(22)X(23)X(24)X(25)X(26)X(27)
#define REP41(X) X(0)X(1)X(2)X(3)X(4)X(5)X(6)X(7)X(8)X(9)X(10)X(11)X(12)X(13)X(14)X(15)X(16)X(17)X(18)X(19)X(20)X(21)X(22)X(23)X(24)X(25)X(26)X(27)X(28)X(29)X(30)X(31)X(32)X(33)X(34)X(35)X(36)X(37)X(38)X(39)X(40)
#define REP64(X) X(0)X(1)X(2)X(3)X(4)X(5)X(6)X(7)X(8)X(9)X(10)X(11)X(12)X(13)X(14)X(15)X(16)X(17)X(18)X(19)X(20)X(21)X(22)X(23)X(24)X(25)X(26)X(27)X(28)X(29)X(30)X(31)X(32)X(33)X(34)X(35)X(36)X(37)X(38)X(39)X(40)X(41)X(42)X(43)X(44)X(45)X(46)X(47)X(48)X(49)X(50)X(51)X(52)X(53)X(54)X(55)X(56)X(57)X(58)X(59)X(60)X(61)X(62)X(63)

typedef const float* fp;

__device__ __forceinline__ float rlf(float v, int q){
  return __int_as_float(__builtin_amdgcn_readlane(__float_as_int(v), q));
}
__device__ __forceinline__ float fsig(float z){
  z = fminf(fmaxf(z, -30.f), 30.f);
  return 1.f / (1.f + __expf(-z));
}
__device__ __forceinline__ float ftanh(float z){
  z = fminf(fmaxf(z, -15.f), 15.f);
  float e = __expf(2.f * z);
  return (e - 1.f) / (e + 1.f);
}

// ---------------- zero scratch ----------------
__global__ void zero_kernel(float* __restrict__ p, int n){
  for (int i = blockIdx.x * blockDim.x + threadIdx.x; i < n; i += gridDim.x * blockDim.x)
    p[i] = 0.f;
}

// ---------------- embedding: x = atom_fea @ emb_W + emb_b ----------------
// wave per 8 atoms; lane = output channel (64). 92 W regs named -> VGPRs.
__global__ __launch_bounds__(256, 2) void emb_kernel(
    fp __restrict__ af, fp __restrict__ W, fp __restrict__ b,
    float* __restrict__ x)
{
  const int lane = threadIdx.x & 63, w = threadIdx.x >> 6;
#define EA(k) float wa##k = W[k * FD + lane];
  REP64(EA)
#undef EA
#define EB(k) float wb##k = W[(k + 64) * FD + lane];
  REP28(EB)
#undef EB
  const float bias = b[lane];
  const int base = blockIdx.x * 32 + w * 8;
  #pragma unroll 1
  for (int it = 0; it < 8; ++it){
    const int i = base + it;
    float ev0 = af[i * ORIGF + lane];
    float ev1 = (lane < 28) ? af[i * ORIGF + 64 + lane] : 0.f;
    float acc = bias;
#define FA(k) acc = fmaf(rlf(ev0, k), wa##k, acc);
    REP64(FA)
#undef FA
#define FB(k) acc = fmaf(rlf(ev1, k), wb##k, acc);
    REP28(FB)
#undef FB
    x[i * FD + lane] = acc;
  }
}

// ---------------- stw: out[N][128] = xin[N][64] @ W[64][128] (+bias) ----------------
// 1 output channel per lane (64 W regs). Wave pair covers both halves;
// block = 4 waves = 2 pairs x 16 atoms = 32 atoms.
__global__ __launch_bounds__(256, 4) void stw_kernel(
    const float* __restrict__ xin, fp __restrict__ W, fp __restrict__ bias,
    float* __restrict__ out)
{
  const int lane = threadIdx.x & 63, w = threadIdx.x >> 6;
  const int ch = (w & 1) * 64 + lane;
#define SW(k) float wv##k = W[k * 128 + ch];
  REP64(SW)
#undef SW
  const float bb = bias ? bias[ch] : 0.f;
  const int base = blockIdx.x * 32 + (w >> 1) * 16;
  #pragma unroll 1
  for (int it = 0; it < 16; ++it){
    const int i = base + it;
    float xv = xin[i * FD + lane];
    float acc = bb;
#define SF(k) acc = fmaf(rlf(xv, k), wv##k, acc);
    REP64(SF)
#undef SF
    out[i * 128 + ch] = acc;
  }
}

// ---------------- edge stats: accumulate sum/sumsq of gated over all N*M rows ----------------
__global__ __launch_bounds__(256, 2) void edge_stats_kernel(
    const float* __restrict__ S, const float* __restrict__ T,
    fp __restrict__ nbr, const int* __restrict__ idx,
    fp __restrict__ We, float* __restrict__ p1)   // p1: [NBLK][256] coalesced
{
  const int lane = threadIdx.x & 63, w = threadIdx.x >> 6;
  const int clo = lane, chi = lane + 64;
#define DW(q) float wlo##q = We[q * 128 + clo], whi##q = We[q * 128 + chi];
  REP41(DW)
#undef DW
  float sum_lo = 0.f, ssq_lo = 0.f, sum_hi = 0.f, ssq_hi = 0.f;
  const int base = blockIdx.x * 32 + w * 8;
  #pragma unroll 1
  for (int it = 0; it < 8; ++it){
    const int i = base + it;
    const float slo = S[i * 128 + clo];
    const float shi = S[i * 128 + chi];
    int kk = (lane < MN) ? idx[i * MN + lane] : 0;
    fp nb = nbr + (size_t)i * (MN * NBRF);
    int k0 = __builtin_amdgcn_readlane(kk, 0);
    float tlo = T[k0 * 128 + clo];
    float thi = T[k0 * 128 + chi];
    float ev  = (lane < NBRF) ? nb[lane] : 0.f;
    #pragma unroll 1
    for (int j = 0; j < MN; j++){
      float tlo_n = 0.f, thi_n = 0.f, ev_n = 0.f;
      if (j + 1 < MN){
        int kn = __builtin_amdgcn_readlane(kk, j + 1);
        tlo_n = T[kn * 128 + clo];
        thi_n = T[kn * 128 + chi];
        ev_n  = (lane < NBRF) ? nb[(j + 1) * NBRF + lane] : 0.f;
      }
      float glo = slo + tlo, ghi = shi + thi;
#define EF(q) { float s_ = rlf(ev, q); glo = fmaf(s_, wlo##q, glo); ghi = fmaf(s_, whi##q, ghi); }
      REP41(EF)
#undef EF
      sum_lo += glo; ssq_lo = fmaf(glo, glo, ssq_lo);
      sum_hi += ghi; ssq_hi = fmaf(ghi, ghi, ssq_hi);
      tlo = tlo_n; thi = thi_n; ev = ev_n;
    }
  }
  __shared__ float red[4 * 512];
  red[w * 512 + 2 * clo    ] = sum_lo;
  red[w * 512 + 2 * clo + 1] = ssq_lo;
  red[w * 512 + 2 * chi    ] = sum_hi;
  red[w * 512 + 2 * chi + 1] = ssq_hi;
  __syncthreads();
  const int t = threadIdx.x;            // stat id: (t>>7)*128 channels = sum|ssq
  const int ch = t & 127, which = t >> 7;
  float v = 0.f;
  #pragma unroll
  for (int ww = 0; ww < 4; ++ww) v += red[ww * 512 + 2 * ch + which];
  p1[blockIdx.x * 256 + t] = v;
}

// ---------------- edge apply: gated -> BN1 affine -> sig*tanh -> sum_j ----------------
__global__ __launch_bounds__(256, 2) void edge_apply_kernel(
    const float* __restrict__ S, const float* __restrict__ T,
    fp __restrict__ nbr, const int* __restrict__ idx,
    fp __restrict__ We, const float* __restrict__ ss1,
    float* __restrict__ ns, float* __restrict__ p2)   // p2: [NBLK][128]
{
  const int lane = threadIdx.x & 63, w = threadIdx.x >> 6;
  const int clo = lane, chi = lane + 64;
#define DW(q) float wlo##q = We[q * 128 + clo], whi##q = We[q * 128 + chi];
  REP41(DW)
#undef DW
  const float sc_lo = ss1[clo],       sh_lo = ss1[128 + clo];
  const float sc_hi = ss1[chi],       sh_hi = ss1[128 + chi];
  float sum2 = 0.f, ssq2 = 0.f;
  const int base = blockIdx.x * 32 + w * 8;
  #pragma unroll 1
  for (int it = 0; it < 8; ++it){
    const int i = base + it;
    const float slo = S[i * 128 + clo];
    const float shi = S[i * 128 + chi];
    int kk = (lane < MN) ? idx[i * MN + lane] : 0;
    fp nb = nbr + (size_t)i * (MN * NBRF);
    int k0 = __builtin_amdgcn_readlane(kk, 0);
    float tlo = T[k0 * 128 + clo];
    float thi = T[k0 * 128 + chi];
    float ev  = (lane < NBRF) ? nb[lane] : 0.f;
    float acc = 0.f;
    #pragma unroll 1
    for (int j = 0; j < MN; j++){
      float tlo_n = 0.f, thi_n = 0.f, ev_n = 0.f;
      if (j + 1 < MN){
        int kn = __builtin_amdgcn_readlane(kk, j + 1);
        tlo_n = T[kn * 128 + clo];
        thi_n = T[kn * 128 + chi];
        ev_n  = (lane < NBRF) ? nb[(j + 1) * NBRF + lane] : 0.f;
      }
      float glo = slo + tlo, ghi = shi + thi;
#define EF(q) { float s_ = rlf(ev, q); glo = fmaf(s_, wlo##q, glo); ghi = fmaf(s_, whi##q, ghi); }
      REP41(EF)
#undef EF
      float filt = fsig(fmaf(glo, sc_lo, sh_lo));
      float core = ftanh(fmaf(ghi, sc_hi, sh_hi));
      acc = fmaf(filt, core, acc);
      tlo = tlo_n; thi = thi_n; ev = ev_n;
    }
    ns[i * FD + lane] = acc;
    sum2 += acc; ssq2 = fmaf(acc, acc, ssq2);
  }
  __shared__ float red[4 * 128];
  red[w * 128 + 2 * lane    ] = sum2;
  red[w * 128 + 2 * lane + 1] = ssq2;
  __syncthreads();
  const int t = threadIdx.x;
  if (t < 128){
    const int ch = t & 63, which = t >> 6;
    float v = 0.f;
    #pragma unroll
    for (int ww = 0; ww < 4; ++ww) v += red[ww * 128 + 2 * ch + which];
    p2[blockIdx.x * 128 + t] = v;
  }
}

// ---------------- grid reduce of partials (coalesced rows -> atomics, 64-way) ----------------
__global__ void reduce_rows_kernel(const float* __restrict__ p, float* __restrict__ accum,
                                   int nrows, int ncols)
{
  const int t = threadIdx.x;   // blockDim.x == ncols
  float a = 0.f;
  for (int r = blockIdx.x; r < nrows; r += gridDim.x) a += p[r * ncols + t];
  atomicAdd(&accum[t], a);
}

__global__ void finalize1_kernel(const float* __restrict__ acc, fp g, fp b,
                                 float* __restrict__ ss1)
{
  const int c = threadIdx.x;   // 128
  const float inv = 1.f / 1200000.f;
  float mean = acc[c] * inv;
  float var  = fmaxf(acc[128 + c] * inv - mean * mean, 0.f);
  float sc   = g[c] * rsqrtf(var + EPSF);
  ss1[c] = sc;
  ss1[128 + c] = b[c] - mean * sc;
}

__global__ void finalize2_kernel(const float* __restrict__ acc, fp g, fp b,
                                 float* __restrict__ ss2)
{
  const int c = threadIdx.x;   // 64
  const float inv = 1.f / 100000.f;
  float mean = acc[c] * inv;
  float var  = fmaxf(acc[64 + c] * inv - mean * mean, 0.f);
  float sc   = g[c] * rsqrtf(var + EPSF);
  ss2[c] = sc;
  ss2[64 + c] = b[c] - mean * sc;
}

// ---------------- BN2 affine + residual tanh; optional f32 x output copy ----------------
__global__ __launch_bounds__(256) void bn2res_kernel(
    float* __restrict__ x, const float* __restrict__ ns,
    const float* __restrict__ ss2, float* __restrict__ xout)
{
  const int e = (blockIdx.x * 256 + threadIdx.x) * 4;   // grid sized exactly
  const int c = e & 63;
  float4 xv = *(const float4*)(x + e);
  float4 nv = *(const float4*)(ns + e);
  float r0 = ftanh(fmaf(nv.x, ss2[c + 0], ss2[64 + c + 0]) + xv.x);
  float r1 = ftanh(fmaf(nv.y, ss2[c + 1], ss2[64 + c + 1]) + xv.y);
  float r2 = ftanh(fmaf(nv.z, ss2[c + 2], ss2[64 + c + 2]) + xv.z);
  float r3 = ftanh(fmaf(nv.w, ss2[c + 3], ss2[64 + c + 3]) + xv.w);
  *(float4*)(x + e) = make_float4(r0, r1, r2, r3);
  if (xout){
    *(float4*)(xout + e) = make_float4(r0, r1, r2, r3);
  }
}

// ---------------- pooling: per-crystal sum of x + counts (sorted ids, run-accumulate) ----------------
__global__ __launch_bounds__(256) void pool1_kernel(
    const float* __restrict__ x, const int* __restrict__ cid,
    float* __restrict__ csum, float* __restrict__ ccnt)
{
  const int lane = threadIdx.x & 63, w = threadIdx.x >> 6;
  const int wg = blockIdx.x * 4 + w;
  const int i0 = wg * 64;
  if (i0 >= NA) return;
  const int i1 = min(i0 + 64, NA);
  int cur = -1; float acc = 0.f; int run = 0;
  for (int i = i0; i < i1; ++i){
    int cd = cid[i];
    if (cd != cur){
      if (cur >= 0){
        atomicAdd(&csum[cur * FD + lane], acc);
        if (lane == 0) atomicAdd(&ccnt[cur], (float)run);
      }
      cur = cd; acc = 0.f; run = 0;
    }
    acc += x[i * FD + lane];
    run++;
  }
  if (cur >= 0){
    atomicAdd(&csum[cur * FD + lane], acc);
    if (lane == 0) atomicAdd(&ccnt[cur], (float)run);
  }
}

// ---------------- c3 = tanh(crys_mean @ W3 + b3) per crystal ----------------
__global__ void cm3_kernel(const float* __restrict__ csum, const float* __restrict__ ccnt,
                           fp W3, fp b3, float* __restrict__ c3)
{
  const int b = blockIdx.x, t = threadIdx.x;   // 64 threads
  __shared__ float mean[64];
  float inv = 1.f / fmaxf(ccnt[b], 1.f);
  mean[t] = csum[b * FD + t] * inv;
  __syncthreads();
  float acc = b3[t];
  #pragma unroll
  for (int k = 0; k < 64; k++) acc = fmaf(mean[k], W3[k * FD + t], acc);
  c3[b * FD + t] = ftanh(acc);
}

// ---------------- a = sigmoid(<x_i, c3[cid]>); seg-sum of a*x ----------------
__global__ __launch_bounds__(256) void pool2_kernel(
    const float* __restrict__ x, const int* __restrict__ cid,
    const float* __restrict__ c3, float* __restrict__ cfs)
{
  const int lane = threadIdx.x & 63, w = threadIdx.x >> 6;
  const int wg = blockIdx.x * 4 + w;
  const int i0 = wg * 64;
  if (i0 >= NA) return;
  const int i1 = min(i0 + 64, NA);
  int cur = -1; float acc = 0.f;
  for (int i = i0; i < i1; ++i){
    int cd = cid[i];
    if (cd != cur){
      if (cur >= 0) atomicAdd(&cfs[cur * FD + lane], acc);
      cur = cd; acc = 0.f;
    }
    float xv = x[i * FD + lane];
    float p = xv * c3[cd * FD + lane];
    #pragma unroll
    for (int off = 32; off; off >>= 1) p += __shfl_xor(p, off);
    acc = fmaf(fsig(p), xv, acc);
  }
  if (cur >= 0) atomicAdd(&cfs[cur * FD + lane], acc);
}

// ---------------- head: softplus(mean @ fc + b) @ out_W + out_b ----------------
__global__ void head_kernel(const float* __restrict__ cfs, const float* __restrict__ ccnt,
                            fp fcW, fp fcb, fp oW, fp ob,
                            float* __restrict__ outp)
{
  const int b = blockIdx.x, t = threadIdx.x;   // 128 threads
  __shared__ float row[64];
  __shared__ float red[128];
  float inv = 1.f / fmaxf(ccnt[b], 1.f);
  if (t < 64) row[t] = cfs[b * FD + t] * inv;
  __syncthreads();
  float acc = fcb[t];
  #pragma unroll
  for (int k = 0; k < 64; k++) acc = fmaf(row[k], fcW[k * 128 + t], acc);
  float sp = (acc > 20.f) ? acc : log1pf(__expf(acc));
  red[t] = sp * oW[t];
  __syncthreads();
  for (int off = 64; off; off >>= 1){
    if (t < off) red[t] += red[t + off];
    __syncthreads();
  }
  if (t == 0) outp[b] = red[0] + ob[0];
}

// ---------------- workspace layout (floats) ----------------
static const size_t O_X    = 0;            // 6,400,000   x[N][64]
static const size_t O_S    = 6400000;      // 12,800,000  S[N][128]
static const size_t O_T    = 19200000;     // 12,800,000  T[N][128]
static const size_t O_NS   = 32000000;     // 6,400,000   nbr_sumed[N][64]
static const size_t O_P1   = 38400000;     // 800,000     [NBLK][256]
static const size_t O_P2   = 39200000;     // 400,000     [NBLK][128]
static const size_t O_SS1  = 39600000;     // 256
static const size_t O_SS2  = 39600256;     // 128
static const size_t O_G1   = 39600384;     // 256
static const size_t O_G2   = 39600640;     // 128
static const size_t O_CSUM = 39600768;     // 128,000
static const size_t O_CCNT = 39728768;     // 2,000
static const size_t O_C3   = 39730768;     // 128,000
static const size_t O_CFS  = 39858768;     // 128,000
static const size_t O_END  = 39986768;     // ~160 MB

extern "C" void kernel_launch(void* const* d_in, const int* in_sizes, int n_in,
                              void* d_out, int out_size, void* d_ws, size_t ws_size,
                              hipStream_t stream)
{
  (void)in_sizes; (void)n_in; (void)out_size;
  if (ws_size < O_END * sizeof(float)) return;   // visible failure, no corruption

  fp atom_fea = (fp)d_in[0];
  fp nbr_fea  = (fp)d_in[1];
  const int* nbr_idx = (const int*)d_in[2];
  const int* cids    = (const int*)d_in[3];
  fp embW = (fp)d_in[4];
  fp embb = (fp)d_in[5];
  fp convW = (fp)d_in[6];
  fp convb = (fp)d_in[7];
  fp bn1g = (fp)d_in[8];
  fp bn1b = (fp)d_in[9];
  fp bn2g = (fp)d_in[10];
  fp bn2b = (fp)d_in[11];
  fp W3W  = (fp)d_in[12];
  fp W3b  = (fp)d_in[13];
  fp fcW  = (fp)d_in[14];
  fp fcb  = (fp)d_in[15];
  fp oW   = (fp)d_in[16];
  fp ob   = (fp)d_in[17];

  float* out_head = (float*)d_out;
  float* out_x    = out_head + NC;

  float* W  = (float*)d_ws;
  float* x    = W + O_X;
  float* S    = W + O_S;
  float* T    = W + O_T;
  float* ns   = W + O_NS;
  float* p1   = W + O_P1;
  float* p2   = W + O_P2;
  float* ss1  = W + O_SS1;
  float* ss2  = W + O_SS2;
  float* g1s  = W + O_G1;
  float* g2s  = W + O_G2;
  float* csum = W + O_CSUM;
  float* ccnt = W + O_CCNT;
  float* c3   = W + O_C3;
  float* cfs  = W + O_CFS;

  // zero crystal accumulators (csum..cfs contiguous, 386,000 floats)
  zero_kernel<<<128, 256, 0, stream>>>(csum, 386000);

  emb_kernel<<<NBLK, 256, 0, stream>>>(atom_fea, embW, embb, x);

  for (int l = 0; l < 3; ++l){
    fp Wl = convW + (size_t)l * 169 * 128;
    stw_kernel<<<NBLK, 256, 0, stream>>>(x, Wl,            convb + l * 128, S);  // self rows 0..63
    stw_kernel<<<NBLK, 256, 0, stream>>>(x, Wl + 64 * 128, (fp)nullptr,     T);  // nbr rows 64..127
    zero_kernel<<<1, 256, 0, stream>>>(g1s, 384);  // g1s(256)+g2s(128) contiguous
    edge_stats_kernel<<<NBLK, 256, 0, stream>>>(S, T, nbr_fea, nbr_idx, Wl + 128 * 128, p1);
    reduce_rows_kernel<<<64, 256, 0, stream>>>(p1, g1s, NBLK, 256);
    finalize1_kernel<<<1, 128, 0, stream>>>(g1s, bn1g + l * 128, bn1b + l * 128, ss1);
    edge_apply_kernel<<<NBLK, 256, 0, stream>>>(S, T, nbr_fea, nbr_idx, Wl + 128 * 128, ss1, ns, p2);
    reduce_rows_kernel<<<64, 128, 0, stream>>>(p2, g2s, NBLK, 128);
    finalize2_kernel<<<1, 64, 0, stream>>>(g2s, bn2g + l * 64, bn2b + l * 64, ss2);
    bn2res_kernel<<<6250, 256, 0, stream>>>(x, ns, ss2, (l == 2) ? out_x : (float*)nullptr);
  }

  pool1_kernel<<<391, 256, 0, stream>>>(x, cids, csum, ccnt);
  cm3_kernel<<<NC, 64, 0, stream>>>(csum, ccnt, W3W, W3b, c3);
  pool2_kernel<<<391, 256, 0, stream>>>(x, cids, c3, cfs);
  head_kernel<<<NC, 128, 0, stream>>>(cfs, ccnt, fcW, fcb, oW, ob, out_head);
}

// Round 3
// 2547.770 us; speedup vs baseline: 3.8680x; 1.2568x over previous
//
#include <hip/hip_runtime.h>
#include <hip/hip_bf16.h>

// CrystalGraphConvNet forward, MI355X. All tensors FLOAT32.
// d_out = [out(2000), x(6.4M)] float32.
//
// Decomposition: gated = S[i] + T[nbr_idx[i,j]] + e_ij @ W_edge, with
// S = x@W[0:64]+b, T = x@W[64:128] precomputed per atom per layer.
// BN over batch => stats pass + apply pass.
//
// R7 change: stats pass STORES gated (f32, [edge][2*lane] interleaved, 614MB)
// when ws_size permits; apply pass becomes a pure streaming kernel (load float2,
// BN1 affine, sig*tanh, sum_j) -- no second 41x128 GEMM, no readlanes.
// Host branches on ws_size: fallback path is the R4/R6 recompute (neutral).
// R6 post-mortem: launch_bounds(256,2) was a no-op (VGPR=60, occ 38.5%, 461us
// unchanged) -- the 2nd arg only caps registers, can't force the allocator out
// of its AGPR-spill allocation. The ~2.7x VALU inflation in the edge GEMM is
// codegen we can't hint away, so stop paying it twice per layer.

#define NA    100000
#define MN    12
#define NC    2000
#define ORIGF 92
#define NBRF  41
#define FD    64
#define NBLK  3125     // edge-kernel blocks: 3125 * 32 atoms = 100000 exactly
#define EPSF  1e-5f

#define REP28(X) X(0)X(1)X(2)X(3)X(4)X(5)X(6)X(7)X(8)X(9)X(10)X(11)X(12)X(13)X(14)X(15)X(16)X(17)X(18)X(19)X(20)X(21)X(22)X(23)X(24)X(25)X(26)X(27)
#define REP41(X) X(0)X(1)X(2)X(3)X(4)X(5)X(6)X(7)X(8)X(9)X(10)X(11)X(12)X(13)X(14)X(15)X(16)X(17)X(18)X(19)X(20)X(21)X(22)X(23)X(24)X(25)X(26)X(27)X(28)X(29)X(30)X(31)X(32)X(33)X(34)X(35)X(36)X(37)X(38)X(39)X(40)
#define REP64(X) X(0)X(1)X(2)X(3)X(4)X(5)X(6)X(7)X(8)X(9)X(10)X(11)X(12)X(13)X(14)X(15)X(16)X(17)X(18)X(19)X(20)X(21)X(22)X(23)X(24)X(25)X(26)X(27)X(28)X(29)X(30)X(31)X(32)X(33)X(34)X(35)X(36)X(37)X(38)X(39)X(40)X(41)X(42)X(43)X(44)X(45)X(46)X(47)X(48)X(49)X(50)X(51)X(52)X(53)X(54)X(55)X(56)X(57)X(58)X(59)X(60)X(61)X(62)X(63)

typedef const float* fp;

__device__ __forceinline__ float rlf(float v, int q){
  return __int_as_float(__builtin_amdgcn_readlane(__float_as_int(v), q));
}
__device__ __forceinline__ float fsig(float z){
  z = fminf(fmaxf(z, -30.f), 30.f);
  return 1.f / (1.f + __expf(-z));
}
__device__ __forceinline__ float ftanh(float z){
  z = fminf(fmaxf(z, -15.f), 15.f);
  float e = __expf(2.f * z);
  return (e - 1.f) / (e + 1.f);
}

// ---------------- zero scratch ----------------
__global__ void zero_kernel(float* __restrict__ p, int n){
  for (int i = blockIdx.x * blockDim.x + threadIdx.x; i < n; i += gridDim.x * blockDim.x)
    p[i] = 0.f;
}

// ---------------- embedding: x = atom_fea @ emb_W + emb_b ----------------
__global__ __launch_bounds__(256, 2) void emb_kernel(
    fp __restrict__ af, fp __restrict__ W, fp __restrict__ b,
    float* __restrict__ x)
{
  const int lane = threadIdx.x & 63, w = threadIdx.x >> 6;
#define EA(k) float wa##k = W[k * FD + lane];
  REP64(EA)
#undef EA
#define EB(k) float wb##k = W[(k + 64) * FD + lane];
  REP28(EB)
#undef EB
  const float bias = b[lane];
  const int base = blockIdx.x * 32 + w * 8;
  #pragma unroll 1
  for (int it = 0; it < 8; ++it){
    const int i = base + it;
    float ev0 = af[i * ORIGF + lane];
    float ev1 = (lane < 28) ? af[i * ORIGF + 64 + lane] : 0.f;
    float acc = bias;
#define FA(k) acc = fmaf(rlf(ev0, k), wa##k, acc);
    REP64(FA)
#undef FA
#define FB(k) acc = fmaf(rlf(ev1, k), wb##k, acc);
    REP28(FB)
#undef FB
    x[i * FD + lane] = acc;
  }
}

// ---------------- stw: out[N][128] = xin[N][64] @ W[64][128] (+bias) ----------------
__global__ __launch_bounds__(256, 4) void stw_kernel(
    const float* __restrict__ xin, fp __restrict__ W, fp __restrict__ bias,
    float* __restrict__ out)
{
  const int lane = threadIdx.x & 63, w = threadIdx.x >> 6;
  const int ch = (w & 1) * 64 + lane;
#define SW(k) float wv##k = W[k * 128 + ch];
  REP64(SW)
#undef SW
  const float bb = bias ? bias[ch] : 0.f;
  const int base = blockIdx.x * 32 + (w >> 1) * 16;
  #pragma unroll 1
  for (int it = 0; it < 16; ++it){
    const int i = base + it;
    float xv = xin[i * FD + lane];
    float acc = bb;
#define SF(k) acc = fmaf(rlf(xv, k), wv##k, acc);
    REP64(SF)
#undef SF
    out[i * 128 + ch] = acc;
  }
}

// ---------------- edge stats (fallback: no store) ----------------
__global__ __launch_bounds__(256, 2) void edge_stats_kernel(
    const float* __restrict__ S, const float* __restrict__ T,
    fp __restrict__ nbr, const int* __restrict__ idx,
    fp __restrict__ We, float* __restrict__ p1)   // p1: [NBLK][256] coalesced
{
  const int lane = threadIdx.x & 63, w = threadIdx.x >> 6;
  const int clo = lane, chi = lane + 64;
#define DW(q) float wlo##q = We[q * 128 + clo], whi##q = We[q * 128 + chi];
  REP41(DW)
#undef DW
  float sum_lo = 0.f, ssq_lo = 0.f, sum_hi = 0.f, ssq_hi = 0.f;
  const int base = blockIdx.x * 32 + w * 8;
  #pragma unroll 1
  for (int it = 0; it < 8; ++it){
    const int i = base + it;
    const float slo = S[i * 128 + clo];
    const float shi = S[i * 128 + chi];
    int kk = (lane < MN) ? idx[i * MN + lane] : 0;
    fp nb = nbr + (size_t)i * (MN * NBRF);
    int k0 = __builtin_amdgcn_readlane(kk, 0);
    float tlo = T[k0 * 128 + clo];
    float thi = T[k0 * 128 + chi];
    float ev  = (lane < NBRF) ? nb[lane] : 0.f;
    #pragma unroll 1
    for (int j = 0; j < MN; j++){
      float tlo_n = 0.f, thi_n = 0.f, ev_n = 0.f;
      if (j + 1 < MN){
        int kn = __builtin_amdgcn_readlane(kk, j + 1);
        tlo_n = T[kn * 128 + clo];
        thi_n = T[kn * 128 + chi];
        ev_n  = (lane < NBRF) ? nb[(j + 1) * NBRF + lane] : 0.f;
      }
      float glo = slo + tlo, ghi = shi + thi;
#define EF(q) { float s_ = rlf(ev, q); glo = fmaf(s_, wlo##q, glo); ghi = fmaf(s_, whi##q, ghi); }
      REP41(EF)
#undef EF
      sum_lo += glo; ssq_lo = fmaf(glo, glo, ssq_lo);
      sum_hi += ghi; ssq_hi = fmaf(ghi, ghi, ssq_hi);
      tlo = tlo_n; thi = thi_n; ev = ev_n;
    }
  }
  __shared__ float red[4 * 512];
  red[w * 512 + 2 * clo    ] = sum_lo;
  red[w * 512 + 2 * clo + 1] = ssq_lo;
  red[w * 512 + 2 * chi    ] = sum_hi;
  red[w * 512 + 2 * chi + 1] = ssq_hi;
  __syncthreads();
  const int t = threadIdx.x;            // stat id: (t>>7)*128 channels = sum|ssq
  const int ch = t & 127, which = t >> 7;
  float v = 0.f;
  #pragma unroll
  for (int ww = 0; ww < 4; ++ww) v += red[ww * 512 + 2 * ch + which];
  p1[blockIdx.x * 256 + t] = v;
}

// ---------------- edge stats + gated store (big-ws path) ----------------
// gated layout: [edge 1.2M][128] where element 2*lane = glo(ch=lane),
// 2*lane+1 = ghi(ch=lane+64)  -> float2 per lane, 512B/edge coalesced.
__global__ __launch_bounds__(256, 2) void edge_stats_store_kernel(
    const float* __restrict__ S, const float* __restrict__ T,
    fp __restrict__ nbr, const int* __restrict__ idx,
    fp __restrict__ We, float* __restrict__ p1, float* __restrict__ gated)
{
  const int lane = threadIdx.x & 63, w = threadIdx.x >> 6;
  const int clo = lane, chi = lane + 64;
#define DW(q) float wlo##q = We[q * 128 + clo], whi##q = We[q * 128 + chi];
  REP41(DW)
#undef DW
  float sum_lo = 0.f, ssq_lo = 0.f, sum_hi = 0.f, ssq_hi = 0.f;
  const int base = blockIdx.x * 32 + w * 8;
  #pragma unroll 1
  for (int it = 0; it < 8; ++it){
    const int i = base + it;
    const float slo = S[i * 128 + clo];
    const float shi = S[i * 128 + chi];
    int kk = (lane < MN) ? idx[i * MN + lane] : 0;
    fp nb = nbr + (size_t)i * (MN * NBRF);
    float* gb = gated + (((size_t)i * MN) << 7) + 2 * lane;
    int k0 = __builtin_amdgcn_readlane(kk, 0);
    float tlo = T[k0 * 128 + clo];
    float thi = T[k0 * 128 + chi];
    float ev  = (lane < NBRF) ? nb[lane] : 0.f;
    #pragma unroll 1
    for (int j = 0; j < MN; j++){
      float tlo_n = 0.f, thi_n = 0.f, ev_n = 0.f;
      if (j + 1 < MN){
        int kn = __builtin_amdgcn_readlane(kk, j + 1);
        tlo_n = T[kn * 128 + clo];
        thi_n = T[kn * 128 + chi];
        ev_n  = (lane < NBRF) ? nb[(j + 1) * NBRF + lane] : 0.f;
      }
      float glo = slo + tlo, ghi = shi + thi;
#define EF(q) { float s_ = rlf(ev, q); glo = fmaf(s_, wlo##q, glo); ghi = fmaf(s_, whi##q, ghi); }
      REP41(EF)
#undef EF
      *(float2*)(gb + ((size_t)j << 7)) = make_float2(glo, ghi);
      sum_lo += glo; ssq_lo = fmaf(glo, glo, ssq_lo);
      sum_hi += ghi; ssq_hi = fmaf(ghi, ghi, ssq_hi);
      tlo = tlo_n; thi = thi_n; ev = ev_n;
    }
  }
  __shared__ float red[4 * 512];
  red[w * 512 + 2 * clo    ] = sum_lo;
  red[w * 512 + 2 * clo + 1] = ssq_lo;
  red[w * 512 + 2 * chi    ] = sum_hi;
  red[w * 512 + 2 * chi + 1] = ssq_hi;
  __syncthreads();
  const int t = threadIdx.x;
  const int ch = t & 127, which = t >> 7;
  float v = 0.f;
  #pragma unroll
  for (int ww = 0; ww < 4; ++ww) v += red[ww * 512 + 2 * ch + which];
  p1[blockIdx.x * 256 + t] = v;
}

// ---------------- edge apply from stored gated (big-ws path) ----------------
// Pure stream: load float2 gated, BN1 affine, sig*tanh, sum_j -> ns + bn2 stats.
__global__ __launch_bounds__(256, 4) void edge_apply_load_kernel(
    const float* __restrict__ gated, const float* __restrict__ ss1,
    float* __restrict__ ns, float* __restrict__ p2)   // p2: [NBLK][128]
{
  const int lane = threadIdx.x & 63, w = threadIdx.x >> 6;
  const float sc_lo = ss1[lane],      sh_lo = ss1[128 + lane];
  const float sc_hi = ss1[64 + lane], sh_hi = ss1[192 + lane];
  float sum2 = 0.f, ssq2 = 0.f;
  const int base = blockIdx.x * 32 + w * 8;
  #pragma unroll 1
  for (int it = 0; it < 8; ++it){
    const int i = base + it;
    fp gb = gated + (((size_t)i * MN) << 7) + 2 * lane;
    float acc = 0.f;
    #pragma unroll
    for (int j = 0; j < MN; ++j){
      float2 gv = *(const float2*)(gb + ((size_t)j << 7));
      float filt = fsig(fmaf(gv.x, sc_lo, sh_lo));
      float core = ftanh(fmaf(gv.y, sc_hi, sh_hi));
      acc = fmaf(filt, core, acc);
    }
    ns[i * FD + lane] = acc;
    sum2 += acc; ssq2 = fmaf(acc, acc, ssq2);
  }
  __shared__ float red[4 * 128];
  red[w * 128 + 2 * lane    ] = sum2;
  red[w * 128 + 2 * lane + 1] = ssq2;
  __syncthreads();
  const int t = threadIdx.x;
  if (t < 128){
    const int ch = t & 63, which = t >> 6;
    float v = 0.f;
    #pragma unroll
    for (int ww = 0; ww < 4; ++ww) v += red[ww * 128 + 2 * ch + which];
    p2[blockIdx.x * 128 + t] = v;
  }
}

// ---------------- edge apply (fallback: recompute) ----------------
__global__ __launch_bounds__(256, 2) void edge_apply_kernel(
    const float* __restrict__ S, const float* __restrict__ T,
    fp __restrict__ nbr, const int* __restrict__ idx,
    fp __restrict__ We, const float* __restrict__ ss1,
    float* __restrict__ ns, float* __restrict__ p2)   // p2: [NBLK][128]
{
  const int lane = threadIdx.x & 63, w = threadIdx.x >> 6;
  const int clo = lane, chi = lane + 64;
#define DW(q) float wlo##q = We[q * 128 + clo], whi##q = We[q * 128 + chi];
  REP41(DW)
#undef DW
  const float sc_lo = ss1[clo],       sh_lo = ss1[128 + clo];
  const float sc_hi = ss1[chi],       sh_hi = ss1[128 + chi];
  float sum2 = 0.f, ssq2 = 0.f;
  const int base = blockIdx.x * 32 + w * 8;
  #pragma unroll 1
  for (int it = 0; it < 8; ++it){
    const int i = base + it;
    const float slo = S[i * 128 + clo];
    const float shi = S[i * 128 + chi];
    int kk = (lane < MN) ? idx[i * MN + lane] : 0;
    fp nb = nbr + (size_t)i * (MN * NBRF);
    int k0 = __builtin_amdgcn_readlane(kk, 0);
    float tlo = T[k0 * 128 + clo];
    float thi = T[k0 * 128 + chi];
    float ev  = (lane < NBRF) ? nb[lane] : 0.f;
    float acc = 0.f;
    #pragma unroll 1
    for (int j = 0; j < MN; j++){
      float tlo_n = 0.f, thi_n = 0.f, ev_n = 0.f;
      if (j + 1 < MN){
        int kn = __builtin_amdgcn_readlane(kk, j + 1);
        tlo_n = T[kn * 128 + clo];
        thi_n = T[kn * 128 + chi];
        ev_n  = (lane < NBRF) ? nb[(j + 1) * NBRF + lane] : 0.f;
      }
      float glo = slo + tlo, ghi = shi + thi;
#define EF(q) { float s_ = rlf(ev, q); glo = fmaf(s_, wlo##q, glo); ghi = fmaf(s_, whi##q, ghi); }
      REP41(EF)
#undef EF
      float filt = fsig(fmaf(glo, sc_lo, sh_lo));
      float core = ftanh(fmaf(ghi, sc_hi, sh_hi));
      acc = fmaf(filt, core, acc);
      tlo = tlo_n; thi = thi_n; ev = ev_n;
    }
    ns[i * FD + lane] = acc;
    sum2 += acc; ssq2 = fmaf(acc, acc, ssq2);
  }
  __shared__ float red[4 * 128];
  red[w * 128 + 2 * lane    ] = sum2;
  red[w * 128 + 2 * lane + 1] = ssq2;
  __syncthreads();
  const int t = threadIdx.x;
  if (t < 128){
    const int ch = t & 63, which = t >> 6;
    float v = 0.f;
    #pragma unroll
    for (int ww = 0; ww < 4; ++ww) v += red[ww * 128 + 2 * ch + which];
    p2[blockIdx.x * 128 + t] = v;
  }
}

// ---------------- grid reduce of partials (coalesced rows -> atomics, 64-way) ----------------
__global__ void reduce_rows_kernel(const float* __restrict__ p, float* __restrict__ accum,
                                   int nrows, int ncols)
{
  const int t = threadIdx.x;   // blockDim.x == ncols
  float a = 0.f;
  for (int r = blockIdx.x; r < nrows; r += gridDim.x) a += p[r * ncols + t];
  atomicAdd(&accum[t], a);
}

__global__ void finalize1_kernel(const float* __restrict__ acc, fp g, fp b,
                                 float* __restrict__ ss1)
{
  const int c = threadIdx.x;   // 128
  const float inv = 1.f / 1200000.f;
  float mean = acc[c] * inv;
  float var  = fmaxf(acc[128 + c] * inv - mean * mean, 0.f);
  float sc   = g[c] * rsqrtf(var + EPSF);
  ss1[c] = sc;
  ss1[128 + c] = b[c] - mean * sc;
}

__global__ void finalize2_kernel(const float* __restrict__ acc, fp g, fp b,
                                 float* __restrict__ ss2)
{
  const int c = threadIdx.x;   // 64
  const float inv = 1.f / 100000.f;
  float mean = acc[c] * inv;
  float var  = fmaxf(acc[64 + c] * inv - mean * mean, 0.f);
  float sc   = g[c] * rsqrtf(var + EPSF);
  ss2[c] = sc;
  ss2[64 + c] = b[c] - mean * sc;
}

// ---------------- BN2 affine + residual tanh; optional f32 x output copy ----------------
__global__ __launch_bounds__(256) void bn2res_kernel(
    float* __restrict__ x, const float* __restrict__ ns,
    const float* __restrict__ ss2, float* __restrict__ xout)
{
  const int e = (blockIdx.x * 256 + threadIdx.x) * 4;   // grid sized exactly
  const int c = e & 63;
  float4 xv = *(const float4*)(x + e);
  float4 nv = *(const float4*)(ns + e);
  float r0 = ftanh(fmaf(nv.x, ss2[c + 0], ss2[64 + c + 0]) + xv.x);
  float r1 = ftanh(fmaf(nv.y, ss2[c + 1], ss2[64 + c + 1]) + xv.y);
  float r2 = ftanh(fmaf(nv.z, ss2[c + 2], ss2[64 + c + 2]) + xv.z);
  float r3 = ftanh(fmaf(nv.w, ss2[c + 3], ss2[64 + c + 3]) + xv.w);
  *(float4*)(x + e) = make_float4(r0, r1, r2, r3);
  if (xout){
    *(float4*)(xout + e) = make_float4(r0, r1, r2, r3);
  }
}

// ---------------- pooling: per-crystal sum of x + counts (sorted ids, run-accumulate) ----------------
__global__ __launch_bounds__(256) void pool1_kernel(
    const float* __restrict__ x, const int* __restrict__ cid,
    float* __restrict__ csum, float* __restrict__ ccnt)
{
  const int lane = threadIdx.x & 63, w = threadIdx.x >> 6;
  const int wg = blockIdx.x * 4 + w;
  const int i0 = wg * 64;
  if (i0 >= NA) return;
  const int i1 = min(i0 + 64, NA);
  int cur = -1; float acc = 0.f; int run = 0;
  for (int i = i0; i < i1; ++i){
    int cd = cid[i];
    if (cd != cur){
      if (cur >= 0){
        atomicAdd(&csum[cur * FD + lane], acc);
        if (lane == 0) atomicAdd(&ccnt[cur], (float)run);
      }
      cur = cd; acc = 0.f; run = 0;
    }
    acc += x[i * FD + lane];
    run++;
  }
  if (cur >= 0){
    atomicAdd(&csum[cur * FD + lane], acc);
    if (lane == 0) atomicAdd(&ccnt[cur], (float)run);
  }
}

// ---------------- c3 = tanh(crys_mean @ W3 + b3) per crystal ----------------
__global__ void cm3_kernel(const float* __restrict__ csum, const float* __restrict__ ccnt,
                           fp W3, fp b3, float* __restrict__ c3)
{
  const int b = blockIdx.x, t = threadIdx.x;   // 64 threads
  __shared__ float mean[64];
  float inv = 1.f / fmaxf(ccnt[b], 1.f);
  mean[t] = csum[b * FD + t] * inv;
  __syncthreads();
  float acc = b3[t];
  #pragma unroll
  for (int k = 0; k < 64; k++) acc = fmaf(mean[k], W3[k * FD + t], acc);
  c3[b * FD + t] = ftanh(acc);
}

// ---------------- a = sigmoid(<x_i, c3[cid]>); seg-sum of a*x ----------------
__global__ __launch_bounds__(256) void pool2_kernel(
    const float* __restrict__ x, const int* __restrict__ cid,
    const float* __restrict__ c3, float* __restrict__ cfs)
{
  const int lane = threadIdx.x & 63, w = threadIdx.x >> 6;
  const int wg = blockIdx.x * 4 + w;
  const int i0 = wg * 64;
  if (i0 >= NA) return;
  const int i1 = min(i0 + 64, NA);
  int cur = -1; float acc = 0.f;
  for (int i = i0; i < i1; ++i){
    int cd = cid[i];
    if (cd != cur){
      if (cur >= 0) atomicAdd(&cfs[cur * FD + lane], acc);
      cur = cd; acc = 0.f;
    }
    float xv = x[i * FD + lane];
    float p = xv * c3[cd * FD + lane];
    #pragma unroll
    for (int off = 32; off; off >>= 1) p += __shfl_xor(p, off);
    acc = fmaf(fsig(p), xv, acc);
  }
  if (cur >= 0) atomicAdd(&cfs[cur * FD + lane], acc);
}

// ---------------- head: softplus(mean @ fc + b) @ out_W + out_b ----------------
__global__ void head_kernel(const float* __restrict__ cfs, const float* __restrict__ ccnt,
                            fp fcW, fp fcb, fp oW, fp ob,
                            float* __restrict__ outp)
{
  const int b = blockIdx.x, t = threadIdx.x;   // 128 threads
  __shared__ float row[64];
  __shared__ float red[128];
  float inv = 1.f / fmaxf(ccnt[b], 1.f);
  if (t < 64) row[t] = cfs[b * FD + t] * inv;
  __syncthreads();
  float acc = fcb[t];
  #pragma unroll
  for (int k = 0; k < 64; k++) acc = fmaf(row[k], fcW[k * 128 + t], acc);
  float sp = (acc > 20.f) ? acc : log1pf(__expf(acc));
  red[t] = sp * oW[t];
  __syncthreads();
  for (int off = 64; off; off >>= 1){
    if (t < off) red[t] += red[t + off];
    __syncthreads();
  }
  if (t == 0) outp[b] = red[0] + ob[0];
}

// ---------------- workspace layout (floats) ----------------
static const size_t O_X    = 0;            // 6,400,000   x[N][64]
static const size_t O_S    = 6400000;      // 12,800,000  S[N][128]
static const size_t O_T    = 19200000;     // 12,800,000  T[N][128]
static const size_t O_NS   = 32000000;     // 6,400,000   nbr_sumed[N][64]
static const size_t O_P1   = 38400000;     // 800,000     [NBLK][256]
static const size_t O_P2   = 39200000;     // 400,000     [NBLK][128]
static const size_t O_SS1  = 39600000;     // 256
static const size_t O_SS2  = 39600256;     // 128
static const size_t O_G1   = 39600384;     // 256
static const size_t O_G2   = 39600640;     // 128
static const size_t O_CSUM = 39600768;     // 128,000
static const size_t O_CCNT = 39728768;     // 2,000
static const size_t O_C3   = 39730768;     // 128,000
static const size_t O_CFS  = 39858768;     // 128,000
static const size_t O_END  = 39986768;     // ~160 MB (fallback minimum)
static const size_t O_GATED= 39986768;     // 153,600,000  gated[1.2M][128]
static const size_t O_END2 = 193586768;    // ~774 MB (big path)

extern "C" void kernel_launch(void* const* d_in, const int* in_sizes, int n_in,
                              void* d_out, int out_size, void* d_ws, size_t ws_size,
                              hipStream_t stream)
{
  (void)in_sizes; (void)n_in; (void)out_size;
  if (ws_size < O_END * sizeof(float)) return;   // visible failure, no corruption
  const bool big = ws_size >= O_END2 * sizeof(float);

  fp atom_fea = (fp)d_in[0];
  fp nbr_fea  = (fp)d_in[1];
  const int* nbr_idx = (const int*)d_in[2];
  const int* cids    = (const int*)d_in[3];
  fp embW = (fp)d_in[4];
  fp embb = (fp)d_in[5];
  fp convW = (fp)d_in[6];
  fp convb = (fp)d_in[7];
  fp bn1g = (fp)d_in[8];
  fp bn1b = (fp)d_in[9];
  fp bn2g = (fp)d_in[10];
  fp bn2b = (fp)d_in[11];
  fp W3W  = (fp)d_in[12];
  fp W3b  = (fp)d_in[13];
  fp fcW  = (fp)d_in[14];
  fp fcb  = (fp)d_in[15];
  fp oW   = (fp)d_in[16];
  fp ob   = (fp)d_in[17];

  float* out_head = (float*)d_out;
  float* out_x    = out_head + NC;

  float* W  = (float*)d_ws;
  float* x    = W + O_X;
  float* S    = W + O_S;
  float* T    = W + O_T;
  float* ns   = W + O_NS;
  float* p1   = W + O_P1;
  float* p2   = W + O_P2;
  float* ss1  = W + O_SS1;
  float* ss2  = W + O_SS2;
  float* g1s  = W + O_G1;
  float* g2s  = W + O_G2;
  float* csum = W + O_CSUM;
  float* ccnt = W + O_CCNT;
  float* c3   = W + O_C3;
  float* cfs  = W + O_CFS;
  float* gated= W + O_GATED;

  // zero crystal accumulators (csum..cfs contiguous, 386,000 floats)
  zero_kernel<<<128, 256, 0, stream>>>(csum, 386000);

  emb_kernel<<<NBLK, 256, 0, stream>>>(atom_fea, embW, embb, x);

  for (int l = 0; l < 3; ++l){
    fp Wl = convW + (size_t)l * 169 * 128;
    stw_kernel<<<NBLK, 256, 0, stream>>>(x, Wl,            convb + l * 128, S);  // self rows 0..63
    stw_kernel<<<NBLK, 256, 0, stream>>>(x, Wl + 64 * 128, (fp)nullptr,     T);  // nbr rows 64..127
    zero_kernel<<<1, 256, 0, stream>>>(g1s, 384);  // g1s(256)+g2s(128) contiguous
    if (big){
      edge_stats_store_kernel<<<NBLK, 256, 0, stream>>>(S, T, nbr_fea, nbr_idx, Wl + 128 * 128, p1, gated);
      reduce_rows_kernel<<<64, 256, 0, stream>>>(p1, g1s, NBLK, 256);
      finalize1_kernel<<<1, 128, 0, stream>>>(g1s, bn1g + l * 128, bn1b + l * 128, ss1);
      edge_apply_load_kernel<<<NBLK, 256, 0, stream>>>(gated, ss1, ns, p2);
    } else {
      edge_stats_kernel<<<NBLK, 256, 0, stream>>>(S, T, nbr_fea, nbr_idx, Wl + 128 * 128, p1);
      reduce_rows_kernel<<<64, 256, 0, stream>>>(p1, g1s, NBLK, 256);
      finalize1_kernel<<<1, 128, 0, stream>>>(g1s, bn1g + l * 128, bn1b + l * 128, ss1);
      edge_apply_kernel<<<NBLK, 256, 0, stream>>>(S, T, nbr_fea, nbr_idx, Wl + 128 * 128, ss1, ns, p2);
    }
    reduce_rows_kernel<<<64, 128, 0, stream>>>(p2, g2s, NBLK, 128);
    finalize2_kernel<<<1, 64, 0, stream>>>(g2s, bn2g + l * 64, bn2b + l * 64, ss2);
    bn2res_kernel<<<6250, 256, 0, stream>>>(x, ns, ss2, (l == 2) ? out_x : (float*)nullptr);
  }

  pool1_kernel<<<391, 256, 0, stream>>>(x, cids, csum, ccnt);
  cm3_kernel<<<NC, 64, 0, stream>>>(csum, ccnt, W3W, W3b, c3);
  pool2_kernel<<<391, 256, 0, stream>>>(x, cids, c3, cfs);
  head_kernel<<<NC, 128, 0, stream>>>(cfs, ccnt, fcW, fcb, oW, ob, out_head);
}